// Round 1
// baseline (2205.869 us; speedup 1.0000x reference)
//
#include <hip/hip_runtime.h>
#include <hip/hip_bf16.h>

// GCN: 3x GCNConv(relu) + mean-pool + linear + log_softmax
// N=100000 nodes, E=1600000 edges, F=128 -> 64 -> 64 -> 64, 256 graphs, 15 classes.

#define N_GRAPHS 256
#define HIDDEN 64
#define N_CLASSES 15

// ---------------- degree histogram ----------------
__global__ void hist_kernel(const int* __restrict__ dst, int* __restrict__ deg, int E) {
    for (int e = blockIdx.x * blockDim.x + threadIdx.x; e < E; e += gridDim.x * blockDim.x) {
        atomicAdd(&deg[dst[e]], 1);
    }
}

__global__ void dinv_kernel(const int* __restrict__ deg, float* __restrict__ dinv, int n) {
    int i = blockIdx.x * blockDim.x + threadIdx.x;
    if (i < n) {
        // self-loop adds 1 to every node's degree -> always > 0
        dinv[i] = rsqrtf((float)(deg[i] + 1));
    }
}

// ---------------- exclusive scan (single block, 1024 threads) ----------------
__global__ __launch_bounds__(1024) void scan_kernel(const int* __restrict__ deg,
                                                    int* __restrict__ rowptr, int n) {
    __shared__ int sums[1024];
    int tid = threadIdx.x;
    int chunk = (n + 1023) / 1024;
    int start = tid * chunk;
    int end = start + chunk;
    if (end > n) end = n;
    int s = 0;
    for (int i = start; i < end; ++i) s += deg[i];
    sums[tid] = s;
    __syncthreads();
    for (int off = 1; off < 1024; off <<= 1) {
        int v = (tid >= off) ? sums[tid - off] : 0;
        __syncthreads();
        sums[tid] += v;
        __syncthreads();
    }
    int run = (tid == 0) ? 0 : sums[tid - 1];
    for (int i = start; i < end; ++i) { rowptr[i] = run; run += deg[i]; }
    if (tid == 0) rowptr[n] = sums[1023];
}

// ---------------- CSR scatter ----------------
__global__ void scatter_kernel(const int* __restrict__ src, const int* __restrict__ dst,
                               const int* __restrict__ rowptr, int* __restrict__ fill,
                               const float* __restrict__ dinv, int* __restrict__ col,
                               float* __restrict__ nrm, int E) {
    for (int e = blockIdx.x * blockDim.x + threadIdx.x; e < E; e += gridDim.x * blockDim.x) {
        int d = dst[e], s = src[e];
        int pos = rowptr[d] + atomicAdd(&fill[d], 1);
        col[pos] = s;
        nrm[pos] = dinv[s] * dinv[d];
    }
}

// ---------------- dense xw = X @ W  (W: [FIN x 64] staged in LDS) ----------------
template <int FIN>
__global__ void gemm_kernel(const float* __restrict__ X, const float* __restrict__ W,
                            float* __restrict__ XW, int n) {
    __shared__ float wlds[FIN * 64];
    for (int i = threadIdx.x; i < FIN * 64; i += blockDim.x) wlds[i] = W[i];
    __syncthreads();
    int lane = threadIdx.x & 63;
    int wid = (blockIdx.x * blockDim.x + threadIdx.x) >> 6;
    int nwaves = (gridDim.x * blockDim.x) >> 6;
    for (int row = wid; row < n; row += nwaves) {
        const float* xr = X + (size_t)row * FIN;
        float acc = 0.f;
#pragma unroll
        for (int k = 0; k < FIN; k += 4) {
            float4 xv = *reinterpret_cast<const float4*>(xr + k);
            acc += xv.x * wlds[(k + 0) * 64 + lane];
            acc += xv.y * wlds[(k + 1) * 64 + lane];
            acc += xv.z * wlds[(k + 2) * 64 + lane];
            acc += xv.w * wlds[(k + 3) * 64 + lane];
        }
        XW[(size_t)row * 64 + lane] = acc;
    }
}

// ---------------- CSR aggregation: out = relu(sum_e nrm*xw[src] + dinv^2*xw[i] + b) ----------------
__global__ void aggregate_kernel(const float* __restrict__ XW, const int* __restrict__ rowptr,
                                 const int* __restrict__ col, const float* __restrict__ nrm,
                                 const float* __restrict__ dinv, const float* __restrict__ bias,
                                 float* __restrict__ OUT, int n) {
    int lane = threadIdx.x & 63;
    int wid = (blockIdx.x * blockDim.x + threadIdx.x) >> 6;
    int nwaves = (gridDim.x * blockDim.x) >> 6;
    float b = bias[lane];
    for (int i = wid; i < n; i += nwaves) {
        float di = dinv[i];
        float acc = di * di * XW[(size_t)i * 64 + lane];
        int p0 = rowptr[i], p1 = rowptr[i + 1];
        for (int p = p0; p < p1; ++p) {
            int s = col[p];
            float w = nrm[p];
            acc += w * XW[(size_t)s * 64 + lane];
        }
        acc += b;
        OUT[(size_t)i * 64 + lane] = acc > 0.f ? acc : 0.f;
    }
}

// ---------------- mean pool (batch is sorted) ----------------
__global__ void pool_kernel(const float* __restrict__ H, const int* __restrict__ batch,
                            float* __restrict__ pooled, int n) {
    int g = blockIdx.x;
    // lower_bound(batch, g) / lower_bound(batch, g+1)
    int lo = 0, hi = n;
    while (lo < hi) { int mid = (lo + hi) >> 1; if (batch[mid] < g) lo = mid + 1; else hi = mid; }
    int start = lo;
    lo = 0; hi = n;
    while (lo < hi) { int mid = (lo + hi) >> 1; if (batch[mid] < g + 1) lo = mid + 1; else hi = mid; }
    int end = lo;

    int lane = threadIdx.x & 63;
    int w = threadIdx.x >> 6;  // 0..3
    __shared__ float part[4][64];
    float acc = 0.f;
    for (int i = start + w; i < end; i += 4) acc += H[(size_t)i * 64 + lane];
    part[w][lane] = acc;
    __syncthreads();
    if (w == 0) {
        float s = part[0][lane] + part[1][lane] + part[2][lane] + part[3][lane];
        float cnt = (float)(end - start);
        pooled[g * 64 + lane] = s / fmaxf(cnt, 1.0f);
    }
}

// ---------------- head: logits = pooled @ fc_w + fc_b; log_softmax ----------------
__global__ void head_kernel(const float* __restrict__ pooled, const float* __restrict__ fcw,
                            const float* __restrict__ fcb, float* __restrict__ out) {
    __shared__ float w[64 * N_CLASSES];
    __shared__ float bb[N_CLASSES];
    for (int i = threadIdx.x; i < 64 * N_CLASSES; i += blockDim.x) w[i] = fcw[i];
    if (threadIdx.x < N_CLASSES) bb[threadIdx.x] = fcb[threadIdx.x];
    __syncthreads();
    int g = threadIdx.x;  // 256 threads, one per graph
    float logits[N_CLASSES];
    float m = -1e30f;
    const float* pr = pooled + g * 64;
    for (int c = 0; c < N_CLASSES; ++c) {
        float acc = bb[c];
        for (int k = 0; k < 64; ++k) acc += pr[k] * w[k * N_CLASSES + c];
        logits[c] = acc;
        m = fmaxf(m, acc);
    }
    float se = 0.f;
    for (int c = 0; c < N_CLASSES; ++c) se += expf(logits[c] - m);
    float lse = m + logf(se);
    for (int c = 0; c < N_CLASSES; ++c) out[g * N_CLASSES + c] = logits[c] - lse;
}

extern "C" void kernel_launch(void* const* d_in, const int* in_sizes, int n_in,
                              void* d_out, int out_size, void* d_ws, size_t ws_size,
                              hipStream_t stream) {
    const float* x    = (const float*)d_in[0];
    const float* w1   = (const float*)d_in[1];
    const float* b1   = (const float*)d_in[2];
    const float* w2   = (const float*)d_in[3];
    const float* b2   = (const float*)d_in[4];
    const float* w3   = (const float*)d_in[5];
    const float* b3   = (const float*)d_in[6];
    const float* fcw  = (const float*)d_in[7];
    const float* fcb  = (const float*)d_in[8];
    const int*   ei   = (const int*)d_in[9];
    const int*   batch = (const int*)d_in[10];

    const int N = in_sizes[10];       // 100000
    const int E = in_sizes[9] / 2;    // 1600000
    const int* src = ei;
    const int* dst = ei + E;

    // workspace carve-out
    char* ws = (char*)d_ws;
    size_t off = 0;
    auto alloc = [&](size_t bytes) -> void* {
        void* p = ws + off;
        off += (bytes + 255) & ~(size_t)255;
        return p;
    };
    int*   deg    = (int*)alloc((size_t)N * 4);
    int*   rowptr = (int*)alloc(((size_t)N + 1) * 4);
    int*   fill   = (int*)alloc((size_t)N * 4);
    int*   col    = (int*)alloc((size_t)E * 4);
    float* nrm    = (float*)alloc((size_t)E * 4);
    float* dinv   = (float*)alloc((size_t)N * 4);
    float* bufA   = (float*)alloc((size_t)N * 64 * 4);  // xw
    float* bufB   = (float*)alloc((size_t)N * 64 * 4);  // h
    float* pooled = (float*)alloc((size_t)N_GRAPHS * 64 * 4);
    (void)ws_size;

    hipMemsetAsync(deg, 0, (size_t)N * 4, stream);
    hipMemsetAsync(fill, 0, (size_t)N * 4, stream);

    const int GB = 2048;  // grid-stride blocks

    hist_kernel<<<GB, 256, 0, stream>>>(dst, deg, E);
    dinv_kernel<<<(N + 255) / 256, 256, 0, stream>>>(deg, dinv, N);
    scan_kernel<<<1, 1024, 0, stream>>>(deg, rowptr, N);
    scatter_kernel<<<GB, 256, 0, stream>>>(src, dst, rowptr, fill, dinv, col, nrm, E);

    // layer 1: x[N,128] @ w1 -> bufA; aggregate -> bufB
    gemm_kernel<128><<<GB, 256, 0, stream>>>(x, w1, bufA, N);
    aggregate_kernel<<<GB, 256, 0, stream>>>(bufA, rowptr, col, nrm, dinv, b1, bufB, N);
    // layer 2
    gemm_kernel<64><<<GB, 256, 0, stream>>>(bufB, w2, bufA, N);
    aggregate_kernel<<<GB, 256, 0, stream>>>(bufA, rowptr, col, nrm, dinv, b2, bufB, N);
    // layer 3
    gemm_kernel<64><<<GB, 256, 0, stream>>>(bufB, w3, bufA, N);
    aggregate_kernel<<<GB, 256, 0, stream>>>(bufA, rowptr, col, nrm, dinv, b3, bufB, N);

    pool_kernel<<<N_GRAPHS, 256, 0, stream>>>(bufB, batch, pooled, N);
    head_kernel<<<1, 256, 0, stream>>>(pooled, fcw, fcb, (float*)d_out);
}

// Round 2
// 626.848 us; speedup vs baseline: 3.5190x; 3.5190x over previous
//
#include <hip/hip_runtime.h>
#include <hip/hip_bf16.h>

// GCN: 3x GCNConv(relu) + mean-pool + linear + log_softmax
// N=100000 nodes, E=1600000 edges, F=128 -> 64 -> 64 -> 64, 256 graphs, 15 classes.
//
// Round 2 structure:
//  - CSR build (hist/dinv/scan/scatter) with packed (col, nrm) int2
//  - GEMM: 32-row tiles staged in LDS, wave = 8 rows x 64 cols register-blocked,
//    output stored as bf16 (the gather table)
//  - Aggregate: wave-per-row CSR, 4-way unrolled edge loop, bf16 gathers, fp32 accum

#define N_GRAPHS 256
#define HIDDEN 64
#define N_CLASSES 15
#define TILE_ROWS 32

__device__ __forceinline__ float bf2f(ushort u) {
    return __uint_as_float(((unsigned int)u) << 16);
}
__device__ __forceinline__ ushort f2bf(float f) {
    __hip_bfloat16 h = __float2bfloat16(f);  // RNE
    return *reinterpret_cast<ushort*>(&h);
}

// ---------------- degree histogram ----------------
__global__ void hist_kernel(const int* __restrict__ dst, int* __restrict__ deg, int E) {
    for (int e = blockIdx.x * blockDim.x + threadIdx.x; e < E; e += gridDim.x * blockDim.x) {
        atomicAdd(&deg[dst[e]], 1);
    }
}

__global__ void dinv_kernel(const int* __restrict__ deg, float* __restrict__ dinv, int n) {
    int i = blockIdx.x * blockDim.x + threadIdx.x;
    if (i < n) dinv[i] = rsqrtf((float)(deg[i] + 1));  // +1 = self-loop
}

// ---------------- exclusive scan (single block, 1024 threads) ----------------
__global__ __launch_bounds__(1024) void scan_kernel(const int* __restrict__ deg,
                                                    int* __restrict__ rowptr, int n) {
    __shared__ int sums[1024];
    int tid = threadIdx.x;
    int chunk = (n + 1023) / 1024;
    int start = tid * chunk;
    int end = start + chunk;
    if (end > n) end = n;
    int s = 0;
    for (int i = start; i < end; ++i) s += deg[i];
    sums[tid] = s;
    __syncthreads();
    for (int off = 1; off < 1024; off <<= 1) {
        int v = (tid >= off) ? sums[tid - off] : 0;
        __syncthreads();
        sums[tid] += v;
        __syncthreads();
    }
    int run = (tid == 0) ? 0 : sums[tid - 1];
    for (int i = start; i < end; ++i) { rowptr[i] = run; run += deg[i]; }
    if (tid == 0) rowptr[n] = sums[1023];
}

// ---------------- CSR scatter: packed (col, nrm-bits) ----------------
__global__ void scatter_kernel(const int* __restrict__ src, const int* __restrict__ dst,
                               const int* __restrict__ rowptr, int* __restrict__ fill,
                               const float* __restrict__ dinv, int2* __restrict__ cn, int E) {
    for (int e = blockIdx.x * blockDim.x + threadIdx.x; e < E; e += gridDim.x * blockDim.x) {
        int d = dst[e], s = src[e];
        int pos = rowptr[d] + atomicAdd(&fill[d], 1);
        cn[pos] = make_int2(s, __float_as_int(dinv[s] * dinv[d]));
    }
}

// ---------------- GEMM: XW(bf16) = X @ W, tiled ----------------
// block = 256 threads (4 waves). One 32-row tile per block (grid-stride).
// LDS: X-tile [32][FIN] + W [FIN][64]. Wave w computes rows w*8..w*8+7, lane = col.
template <int FIN>
__global__ __launch_bounds__(256) void gemm_tile_kernel(const float* __restrict__ X,
                                                        const float* __restrict__ W,
                                                        ushort* __restrict__ XWB, int n) {
    __shared__ float xt[TILE_ROWS][FIN];
    __shared__ float wl[FIN * 64];
    for (int i = threadIdx.x; i < FIN * 64; i += 256) wl[i] = W[i];

    int lane = threadIdx.x & 63;
    int w = threadIdx.x >> 6;
    int ntiles = (n + TILE_ROWS - 1) / TILE_ROWS;

    for (int t = blockIdx.x; t < ntiles; t += gridDim.x) {
        int row0 = t * TILE_ROWS;
        __syncthreads();  // xt reuse guard (also covers initial wl stage)
        // stage X tile, coalesced float4
        const int NF4 = TILE_ROWS * FIN / 4;
        for (int i = threadIdx.x; i < NF4; i += 256) {
            int r = i / (FIN / 4), k4 = i % (FIN / 4);
            int row = row0 + r;
            float4 v;
            if (row < n) v = *reinterpret_cast<const float4*>(X + (size_t)row * FIN + k4 * 4);
            else v = make_float4(0.f, 0.f, 0.f, 0.f);
            *reinterpret_cast<float4*>(&xt[r][k4 * 4]) = v;
        }
        __syncthreads();

        int r0 = w * 8;
        float acc[8] = {0.f, 0.f, 0.f, 0.f, 0.f, 0.f, 0.f, 0.f};
#pragma unroll 8
        for (int k = 0; k < FIN; ++k) {
            float wv = wl[k * 64 + lane];
#pragma unroll
            for (int j = 0; j < 8; ++j) acc[j] += xt[r0 + j][k] * wv;
        }
#pragma unroll
        for (int j = 0; j < 8; ++j) {
            int row = row0 + r0 + j;
            if (row < n) XWB[(size_t)row * 64 + lane] = f2bf(acc[j]);
        }
    }
}

// ---------------- CSR aggregation: relu(sum nrm*xw[col] + dinv^2*xw[i] + b) ----------------
__global__ __launch_bounds__(256) void agg_csr_kernel(const ushort* __restrict__ XWB,
                                                      const int* __restrict__ rowptr,
                                                      const int2* __restrict__ cn,
                                                      const float* __restrict__ dinv,
                                                      const float* __restrict__ bias,
                                                      float* __restrict__ OUT, int n) {
    int lane = threadIdx.x & 63;
    int wid = (blockIdx.x * blockDim.x + threadIdx.x) >> 6;
    int nw = (gridDim.x * blockDim.x) >> 6;
    float b = bias[lane];
    for (int i = wid; i < n; i += nw) {
        float di = dinv[i];
        float a0 = di * di * bf2f(XWB[(size_t)i * 64 + lane]);  // self-loop
        float a1 = 0.f, a2 = 0.f, a3 = 0.f;
        int p0 = rowptr[i], p1 = rowptr[i + 1];
        int p = p0;
        for (; p + 4 <= p1; p += 4) {
            int2 e0 = cn[p], e1 = cn[p + 1], e2 = cn[p + 2], e3 = cn[p + 3];
            a0 += __int_as_float(e0.y) * bf2f(XWB[(size_t)e0.x * 64 + lane]);
            a1 += __int_as_float(e1.y) * bf2f(XWB[(size_t)e1.x * 64 + lane]);
            a2 += __int_as_float(e2.y) * bf2f(XWB[(size_t)e2.x * 64 + lane]);
            a3 += __int_as_float(e3.y) * bf2f(XWB[(size_t)e3.x * 64 + lane]);
        }
        for (; p < p1; ++p) {
            int2 e = cn[p];
            a0 += __int_as_float(e.y) * bf2f(XWB[(size_t)e.x * 64 + lane]);
        }
        float acc = a0 + a1 + a2 + a3 + b;
        OUT[(size_t)i * 64 + lane] = fmaxf(acc, 0.f);
    }
}

// ---------------- mean pool (batch is sorted) ----------------
__global__ void pool_kernel(const float* __restrict__ H, const int* __restrict__ batch,
                            float* __restrict__ pooled, int n) {
    int g = blockIdx.x;
    int lo = 0, hi = n;
    while (lo < hi) { int mid = (lo + hi) >> 1; if (batch[mid] < g) lo = mid + 1; else hi = mid; }
    int start = lo;
    lo = 0; hi = n;
    while (lo < hi) { int mid = (lo + hi) >> 1; if (batch[mid] < g + 1) lo = mid + 1; else hi = mid; }
    int end = lo;

    int lane = threadIdx.x & 63;
    int w = threadIdx.x >> 6;
    __shared__ float part[4][64];
    float acc = 0.f;
    for (int i = start + w; i < end; i += 4) acc += H[(size_t)i * 64 + lane];
    part[w][lane] = acc;
    __syncthreads();
    if (w == 0) {
        float s = part[0][lane] + part[1][lane] + part[2][lane] + part[3][lane];
        float cnt = (float)(end - start);
        pooled[g * 64 + lane] = s / fmaxf(cnt, 1.0f);
    }
}

// ---------------- head ----------------
__global__ void head_kernel(const float* __restrict__ pooled, const float* __restrict__ fcw,
                            const float* __restrict__ fcb, float* __restrict__ out) {
    __shared__ float w[64 * N_CLASSES];
    __shared__ float bb[N_CLASSES];
    for (int i = threadIdx.x; i < 64 * N_CLASSES; i += blockDim.x) w[i] = fcw[i];
    if (threadIdx.x < N_CLASSES) bb[threadIdx.x] = fcb[threadIdx.x];
    __syncthreads();
    int g = threadIdx.x;  // 256 threads, one per graph
    float logits[N_CLASSES];
    float m = -1e30f;
    const float* pr = pooled + g * 64;
    for (int c = 0; c < N_CLASSES; ++c) {
        float acc = bb[c];
        for (int k = 0; k < 64; ++k) acc += pr[k] * w[k * N_CLASSES + c];
        logits[c] = acc;
        m = fmaxf(m, acc);
    }
    float se = 0.f;
    for (int c = 0; c < N_CLASSES; ++c) se += expf(logits[c] - m);
    float lse = m + logf(se);
    for (int c = 0; c < N_CLASSES; ++c) out[g * N_CLASSES + c] = logits[c] - lse;
}

extern "C" void kernel_launch(void* const* d_in, const int* in_sizes, int n_in,
                              void* d_out, int out_size, void* d_ws, size_t ws_size,
                              hipStream_t stream) {
    const float* x    = (const float*)d_in[0];
    const float* w1   = (const float*)d_in[1];
    const float* b1   = (const float*)d_in[2];
    const float* w2   = (const float*)d_in[3];
    const float* b2   = (const float*)d_in[4];
    const float* w3   = (const float*)d_in[5];
    const float* b3   = (const float*)d_in[6];
    const float* fcw  = (const float*)d_in[7];
    const float* fcb  = (const float*)d_in[8];
    const int*   ei   = (const int*)d_in[9];
    const int*   batch = (const int*)d_in[10];

    const int N = in_sizes[10];       // 100000
    const int E = in_sizes[9] / 2;    // 1600000
    const int* src = ei;
    const int* dst = ei + E;

    char* ws = (char*)d_ws;
    size_t off = 0;
    auto alloc = [&](size_t bytes) -> void* {
        void* p = ws + off;
        off += (bytes + 255) & ~(size_t)255;
        return p;
    };
    int*    deg    = (int*)alloc((size_t)N * 4);
    int*    rowptr = (int*)alloc(((size_t)N + 1) * 4);
    int*    fill   = (int*)alloc((size_t)N * 4);
    int2*   cn     = (int2*)alloc((size_t)E * 8);
    float*  dinv   = (float*)alloc((size_t)N * 4);
    ushort* xwb    = (ushort*)alloc((size_t)N * 64 * 2);  // bf16 gather table
    float*  bufB   = (float*)alloc((size_t)N * 64 * 4);   // h (fp32)
    float*  pooled = (float*)alloc((size_t)N_GRAPHS * 64 * 4);
    (void)ws_size;

    hipMemsetAsync(deg, 0, (size_t)N * 4, stream);
    hipMemsetAsync(fill, 0, (size_t)N * 4, stream);

    const int GB = 2048;

    hist_kernel<<<GB, 256, 0, stream>>>(dst, deg, E);
    dinv_kernel<<<(N + 255) / 256, 256, 0, stream>>>(deg, dinv, N);
    scan_kernel<<<1, 1024, 0, stream>>>(deg, rowptr, N);
    scatter_kernel<<<GB, 256, 0, stream>>>(src, dst, rowptr, fill, dinv, cn, E);

    int ntiles = (N + TILE_ROWS - 1) / TILE_ROWS;  // 3125

    // layer 1
    gemm_tile_kernel<128><<<ntiles, 256, 0, stream>>>(x, w1, xwb, N);
    agg_csr_kernel<<<GB, 256, 0, stream>>>(xwb, rowptr, cn, dinv, b1, bufB, N);
    // layer 2
    gemm_tile_kernel<64><<<ntiles, 256, 0, stream>>>(bufB, w2, xwb, N);
    agg_csr_kernel<<<GB, 256, 0, stream>>>(xwb, rowptr, cn, dinv, b2, bufB, N);
    // layer 3
    gemm_tile_kernel<64><<<ntiles, 256, 0, stream>>>(bufB, w3, xwb, N);
    agg_csr_kernel<<<GB, 256, 0, stream>>>(xwb, rowptr, cn, dinv, b3, bufB, N);

    pool_kernel<<<N_GRAPHS, 256, 0, stream>>>(bufB, batch, pooled, N);
    head_kernel<<<1, 256, 0, stream>>>(pooled, fcw, fcb, (float*)d_out);
}

// Round 3
// 475.451 us; speedup vs baseline: 4.6395x; 1.3184x over previous
//
#include <hip/hip_runtime.h>
#include <hip/hip_bf16.h>

// GCN: 3x GCNConv(relu) + mean-pool + linear + log_softmax
// N=100000 nodes, E=1600000 edges, F=128 -> 64 -> 64 -> 64, 256 graphs, 15 classes.
//
// Round 3 structure:
//  - CSR build: hist -> 3-phase device-wide scan (fused dinv) -> scatter (packed int2)
//  - GEMM: 32-row tiles staged in LDS, wave = 8 rows x 64 cols register-blocked,
//    output stored as bf16 (the gather table)
//  - Aggregate: wave-per-row CSR, 4-way unrolled edge loop, bf16 gathers, fp32 accum

#define N_GRAPHS 256
#define HIDDEN 64
#define N_CLASSES 15
#define TILE_ROWS 32
#define SCAN_CHUNK 1024  // per block: 256 threads x 4 elements

__device__ __forceinline__ float bf2f(ushort u) {
    return __uint_as_float(((unsigned int)u) << 16);
}
__device__ __forceinline__ ushort f2bf(float f) {
    __hip_bfloat16 h = __float2bfloat16(f);  // RNE
    return *reinterpret_cast<ushort*>(&h);
}

// ---------------- degree histogram ----------------
__global__ void hist_kernel(const int* __restrict__ dst, int* __restrict__ deg, int E) {
    for (int e = blockIdx.x * blockDim.x + threadIdx.x; e < E; e += gridDim.x * blockDim.x) {
        atomicAdd(&deg[dst[e]], 1);
    }
}

// ---------------- 3-phase device-wide exclusive scan of deg -> rowptr ----------------
__global__ __launch_bounds__(256) void scan_a_kernel(const int* __restrict__ deg,
                                                     int* __restrict__ bsum, int n) {
    int base = blockIdx.x * SCAN_CHUNK + threadIdx.x * 4;
    int s = 0;
#pragma unroll
    for (int j = 0; j < 4; ++j) {
        int i = base + j;
        if (i < n) s += deg[i];
    }
    __shared__ int ls[256];
    ls[threadIdx.x] = s;
    __syncthreads();
    for (int off = 128; off > 0; off >>= 1) {
        if (threadIdx.x < off) ls[threadIdx.x] += ls[threadIdx.x + off];
        __syncthreads();
    }
    if (threadIdx.x == 0) bsum[blockIdx.x] = ls[0];
}

// single small block: exclusive-scan the <=256 block sums; also write rowptr[n] = total
__global__ __launch_bounds__(256) void scan_b_kernel(const int* __restrict__ bsum,
                                                     int* __restrict__ boff,
                                                     int* __restrict__ rowptr, int nb, int n) {
    __shared__ int s[256];
    int t = threadIdx.x;
    s[t] = (t < nb) ? bsum[t] : 0;
    __syncthreads();
    for (int off = 1; off < 256; off <<= 1) {
        int v = (t >= off) ? s[t - off] : 0;
        __syncthreads();
        s[t] += v;
        __syncthreads();
    }
    if (t < nb) boff[t] = (t == 0) ? 0 : s[t - 1];
    if (t == 0) rowptr[n] = s[255];  // zeros padded above nb, so s[255] == total
}

// per-block exclusive scan + offset -> rowptr; fused dinv = rsqrt(deg+1)
__global__ __launch_bounds__(256) void scan_c_kernel(const int* __restrict__ deg,
                                                     const int* __restrict__ boff,
                                                     int* __restrict__ rowptr,
                                                     float* __restrict__ dinv, int n) {
    int base = blockIdx.x * SCAN_CHUNK + threadIdx.x * 4;
    int v[4];
    int s = 0;
#pragma unroll
    for (int j = 0; j < 4; ++j) {
        int i = base + j;
        v[j] = (i < n) ? deg[i] : 0;
        s += v[j];
    }
    __shared__ int ls[256];
    ls[threadIdx.x] = s;
    __syncthreads();
    for (int off = 1; off < 256; off <<= 1) {
        int u = (threadIdx.x >= off) ? ls[threadIdx.x - off] : 0;
        __syncthreads();
        ls[threadIdx.x] += u;
        __syncthreads();
    }
    int run = boff[blockIdx.x] + ((threadIdx.x == 0) ? 0 : ls[threadIdx.x - 1]);
#pragma unroll
    for (int j = 0; j < 4; ++j) {
        int i = base + j;
        if (i < n) {
            rowptr[i] = run;
            dinv[i] = rsqrtf((float)(v[j] + 1));  // +1 = self-loop
            run += v[j];
        }
    }
}

// ---------------- CSR scatter: packed (col, nrm-bits) ----------------
__global__ void scatter_kernel(const int* __restrict__ src, const int* __restrict__ dst,
                               const int* __restrict__ rowptr, int* __restrict__ fill,
                               const float* __restrict__ dinv, int2* __restrict__ cn, int E) {
    for (int e = blockIdx.x * blockDim.x + threadIdx.x; e < E; e += gridDim.x * blockDim.x) {
        int d = dst[e], s = src[e];
        int pos = rowptr[d] + atomicAdd(&fill[d], 1);
        cn[pos] = make_int2(s, __float_as_int(dinv[s] * dinv[d]));
    }
}

// ---------------- GEMM: XW(bf16) = X @ W, tiled ----------------
// block = 256 threads (4 waves). One 32-row tile per block (grid-stride).
// LDS: X-tile [32][FIN] + W [FIN][64]. Wave w computes rows w*8..w*8+7, lane = col.
template <int FIN>
__global__ __launch_bounds__(256) void gemm_tile_kernel(const float* __restrict__ X,
                                                        const float* __restrict__ W,
                                                        ushort* __restrict__ XWB, int n) {
    __shared__ float xt[TILE_ROWS][FIN];
    __shared__ float wl[FIN * 64];
    for (int i = threadIdx.x; i < FIN * 64; i += 256) wl[i] = W[i];

    int lane = threadIdx.x & 63;
    int w = threadIdx.x >> 6;
    int ntiles = (n + TILE_ROWS - 1) / TILE_ROWS;

    for (int t = blockIdx.x; t < ntiles; t += gridDim.x) {
        int row0 = t * TILE_ROWS;
        __syncthreads();  // xt reuse guard (also covers initial wl stage)
        const int NF4 = TILE_ROWS * FIN / 4;
        for (int i = threadIdx.x; i < NF4; i += 256) {
            int r = i / (FIN / 4), k4 = i % (FIN / 4);
            int row = row0 + r;
            float4 v;
            if (row < n) v = *reinterpret_cast<const float4*>(X + (size_t)row * FIN + k4 * 4);
            else v = make_float4(0.f, 0.f, 0.f, 0.f);
            *reinterpret_cast<float4*>(&xt[r][k4 * 4]) = v;
        }
        __syncthreads();

        int r0 = w * 8;
        float acc[8] = {0.f, 0.f, 0.f, 0.f, 0.f, 0.f, 0.f, 0.f};
#pragma unroll 8
        for (int k = 0; k < FIN; ++k) {
            float wv = wl[k * 64 + lane];
#pragma unroll
            for (int j = 0; j < 8; ++j) acc[j] += xt[r0 + j][k] * wv;
        }
#pragma unroll
        for (int j = 0; j < 8; ++j) {
            int row = row0 + r0 + j;
            if (row < n) XWB[(size_t)row * 64 + lane] = f2bf(acc[j]);
        }
    }
}

// ---------------- CSR aggregation: relu(sum nrm*xw[col] + dinv^2*xw[i] + b) ----------------
__global__ __launch_bounds__(256) void agg_csr_kernel(const ushort* __restrict__ XWB,
                                                      const int* __restrict__ rowptr,
                                                      const int2* __restrict__ cn,
                                                      const float* __restrict__ dinv,
                                                      const float* __restrict__ bias,
                                                      float* __restrict__ OUT, int n) {
    int lane = threadIdx.x & 63;
    int wid = (blockIdx.x * blockDim.x + threadIdx.x) >> 6;
    int nw = (gridDim.x * blockDim.x) >> 6;
    float b = bias[lane];
    for (int i = wid; i < n; i += nw) {
        float di = dinv[i];
        float a0 = di * di * bf2f(XWB[(size_t)i * 64 + lane]);  // self-loop
        float a1 = 0.f, a2 = 0.f, a3 = 0.f;
        int p0 = rowptr[i], p1 = rowptr[i + 1];
        int p = p0;
        for (; p + 4 <= p1; p += 4) {
            int2 e0 = cn[p], e1 = cn[p + 1], e2 = cn[p + 2], e3 = cn[p + 3];
            a0 += __int_as_float(e0.y) * bf2f(XWB[(size_t)e0.x * 64 + lane]);
            a1 += __int_as_float(e1.y) * bf2f(XWB[(size_t)e1.x * 64 + lane]);
            a2 += __int_as_float(e2.y) * bf2f(XWB[(size_t)e2.x * 64 + lane]);
            a3 += __int_as_float(e3.y) * bf2f(XWB[(size_t)e3.x * 64 + lane]);
        }
        for (; p < p1; ++p) {
            int2 e = cn[p];
            a0 += __int_as_float(e.y) * bf2f(XWB[(size_t)e.x * 64 + lane]);
        }
        float acc = a0 + a1 + a2 + a3 + b;
        OUT[(size_t)i * 64 + lane] = fmaxf(acc, 0.f);
    }
}

// ---------------- mean pool (batch is sorted) ----------------
__global__ void pool_kernel(const float* __restrict__ H, const int* __restrict__ batch,
                            float* __restrict__ pooled, int n) {
    int g = blockIdx.x;
    int lo = 0, hi = n;
    while (lo < hi) { int mid = (lo + hi) >> 1; if (batch[mid] < g) lo = mid + 1; else hi = mid; }
    int start = lo;
    lo = 0; hi = n;
    while (lo < hi) { int mid = (lo + hi) >> 1; if (batch[mid] < g + 1) lo = mid + 1; else hi = mid; }
    int end = lo;

    int lane = threadIdx.x & 63;
    int w = threadIdx.x >> 6;
    __shared__ float part[4][64];
    float acc = 0.f;
    for (int i = start + w; i < end; i += 4) acc += H[(size_t)i * 64 + lane];
    part[w][lane] = acc;
    __syncthreads();
    if (w == 0) {
        float s = part[0][lane] + part[1][lane] + part[2][lane] + part[3][lane];
        float cnt = (float)(end - start);
        pooled[g * 64 + lane] = s / fmaxf(cnt, 1.0f);
    }
}

// ---------------- head ----------------
__global__ void head_kernel(const float* __restrict__ pooled, const float* __restrict__ fcw,
                            const float* __restrict__ fcb, float* __restrict__ out) {
    __shared__ float w[64 * N_CLASSES];
    __shared__ float bb[N_CLASSES];
    for (int i = threadIdx.x; i < 64 * N_CLASSES; i += blockDim.x) w[i] = fcw[i];
    if (threadIdx.x < N_CLASSES) bb[threadIdx.x] = fcb[threadIdx.x];
    __syncthreads();
    int g = threadIdx.x;  // 256 threads, one per graph
    float logits[N_CLASSES];
    float m = -1e30f;
    const float* pr = pooled + g * 64;
    for (int c = 0; c < N_CLASSES; ++c) {
        float acc = bb[c];
        for (int k = 0; k < 64; ++k) acc += pr[k] * w[k * N_CLASSES + c];
        logits[c] = acc;
        m = fmaxf(m, acc);
    }
    float se = 0.f;
    for (int c = 0; c < N_CLASSES; ++c) se += expf(logits[c] - m);
    float lse = m + logf(se);
    for (int c = 0; c < N_CLASSES; ++c) out[g * N_CLASSES + c] = logits[c] - lse;
}

extern "C" void kernel_launch(void* const* d_in, const int* in_sizes, int n_in,
                              void* d_out, int out_size, void* d_ws, size_t ws_size,
                              hipStream_t stream) {
    const float* x    = (const float*)d_in[0];
    const float* w1   = (const float*)d_in[1];
    const float* b1   = (const float*)d_in[2];
    const float* w2   = (const float*)d_in[3];
    const float* b2   = (const float*)d_in[4];
    const float* w3   = (const float*)d_in[5];
    const float* b3   = (const float*)d_in[6];
    const float* fcw  = (const float*)d_in[7];
    const float* fcb  = (const float*)d_in[8];
    const int*   ei   = (const int*)d_in[9];
    const int*   batch = (const int*)d_in[10];

    const int N = in_sizes[10];       // 100000
    const int E = in_sizes[9] / 2;    // 1600000
    const int* src = ei;
    const int* dst = ei + E;

    char* ws = (char*)d_ws;
    size_t off = 0;
    auto alloc = [&](size_t bytes) -> void* {
        void* p = ws + off;
        off += (bytes + 255) & ~(size_t)255;
        return p;
    };
    int*    deg    = (int*)alloc((size_t)N * 4);
    int*    rowptr = (int*)alloc(((size_t)N + 1) * 4);
    int*    fill   = (int*)alloc((size_t)N * 4);
    int2*   cn     = (int2*)alloc((size_t)E * 8);
    float*  dinv   = (float*)alloc((size_t)N * 4);
    ushort* xwb    = (ushort*)alloc((size_t)N * 64 * 2);  // bf16 gather table
    float*  bufB   = (float*)alloc((size_t)N * 64 * 4);   // h (fp32)
    float*  pooled = (float*)alloc((size_t)N_GRAPHS * 64 * 4);
    int*    bsum   = (int*)alloc(256 * 4);
    int*    boff   = (int*)alloc(256 * 4);
    (void)ws_size;

    hipMemsetAsync(deg, 0, (size_t)N * 4, stream);
    hipMemsetAsync(fill, 0, (size_t)N * 4, stream);

    const int GB = 2048;
    const int nb = (N + SCAN_CHUNK - 1) / SCAN_CHUNK;  // 98 blocks

    hist_kernel<<<GB, 256, 0, stream>>>(dst, deg, E);
    scan_a_kernel<<<nb, 256, 0, stream>>>(deg, bsum, N);
    scan_b_kernel<<<1, 256, 0, stream>>>(bsum, boff, rowptr, nb, N);
    scan_c_kernel<<<nb, 256, 0, stream>>>(deg, boff, rowptr, dinv, N);
    scatter_kernel<<<GB, 256, 0, stream>>>(src, dst, rowptr, fill, dinv, cn, E);

    int ntiles = (N + TILE_ROWS - 1) / TILE_ROWS;  // 3125

    // layer 1
    gemm_tile_kernel<128><<<ntiles, 256, 0, stream>>>(x, w1, xwb, N);
    agg_csr_kernel<<<GB, 256, 0, stream>>>(xwb, rowptr, cn, dinv, b1, bufB, N);
    // layer 2
    gemm_tile_kernel<64><<<ntiles, 256, 0, stream>>>(bufB, w2, xwb, N);
    agg_csr_kernel<<<GB, 256, 0, stream>>>(xwb, rowptr, cn, dinv, b2, bufB, N);
    // layer 3
    gemm_tile_kernel<64><<<ntiles, 256, 0, stream>>>(bufB, w3, xwb, N);
    agg_csr_kernel<<<GB, 256, 0, stream>>>(xwb, rowptr, cn, dinv, b3, bufB, N);

    pool_kernel<<<N_GRAPHS, 256, 0, stream>>>(bufB, batch, pooled, N);
    head_kernel<<<1, 256, 0, stream>>>(pooled, fcw, fcb, (float*)d_out);
}